// Round 5
// baseline (201.477 us; speedup 1.0000x reference)
//
#include <hip/hip_runtime.h>

#define B_   16
#define C_   512
#define HW_  1024
#define G_   32
#define CPG  16
#define EPS  1e-5f
#define CHW  ((size_t)C_ * HW_)        // 524288 elements per batch (c,hw)
#define HW2  ((size_t)HW_ * HW_)       // 1048576 elements per batch (hw,hw)

typedef __attribute__((ext_vector_type(8))) short bf16x8;
typedef __attribute__((ext_vector_type(4))) float f32x4;

__device__ inline unsigned short f2bf(float f) {
    union { float f; unsigned u; } v; v.f = f;
    unsigned r = v.u + 0x7fffu + ((v.u >> 16) & 1u);   // RNE
    return (unsigned short)(r >> 16);
}
__device__ inline float bf2f(unsigned short h) {
    union { unsigned u; float f; } v; v.u = (unsigned)h << 16;
    return v.f;
}

__device__ inline void gload_lds16(const void* g, void* lds) {
    __builtin_amdgcn_global_load_lds(
        (const __attribute__((address_space(1))) void*)g,
        (__attribute__((address_space(3))) void*)lds,
        16, 0, 0);
}

// ---------------- fp32 -> bf16 weight convert (all 4 weights, one launch) ----
__global__ __launch_bounds__(256) void f2bf4_kernel(
    const float* __restrict__ w0, const float* __restrict__ w1,
    const float* __restrict__ w2, const float* __restrict__ w3,
    unsigned short* __restrict__ o0, unsigned short* __restrict__ o1,
    unsigned short* __restrict__ o2, unsigned short* __restrict__ o3)
{
    int wsel = blockIdx.x >> 8;
    int blk  = blockIdx.x & 255;
    const float* in = (wsel == 0) ? w0 : (wsel == 1) ? w1 : (wsel == 2) ? w2 : w3;
    unsigned short* out = (wsel == 0) ? o0 : (wsel == 1) ? o1 : (wsel == 2) ? o2 : o3;
    int i = (blk * 256 + threadIdx.x) * 4;
    float4 f = *reinterpret_cast<const float4*>(in + i);
    ushort4 o;
    o.x = f2bf(f.x); o.y = f2bf(f.y); o.z = f2bf(f.z); o.w = f2bf(f.w);
    *reinterpret_cast<ushort4*>(out + i) = o;
}

// ---------------- concat bq||bk -> bqk[1024] ----------------
__global__ __launch_bounds__(256) void bias_concat(
    const float* __restrict__ bq, const float* __restrict__ bk,
    float* __restrict__ bqk)
{
    const float* src = blockIdx.x ? bk : bq;
    bqk[blockIdx.x * 512 + threadIdx.x]       = src[threadIdx.x];
    bqk[blockIdx.x * 512 + 256 + threadIdx.x] = src[256 + threadIdx.x];
}

// ---------------- GN pass 1: per-(b,g) mean / rsqrt(var) ----------------
__global__ __launch_bounds__(256) void gn_stats(const float* __restrict__ x,
                                                float2* __restrict__ stats)
{
    int bg = blockIdx.x;                                  // 0..511
    const float4* xp = reinterpret_cast<const float4*>(x + (size_t)bg * CPG * HW_);
    const int N = CPG * HW_;                              // 16384

    float s = 0.f, ss = 0.f;
#pragma unroll
    for (int k = 0; k < 16; ++k) {
        float4 v = xp[threadIdx.x + k * 256];
        s  += v.x + v.y + v.z + v.w;
        ss += v.x * v.x + v.y * v.y + v.z * v.z + v.w * v.w;
    }
    for (int off = 32; off; off >>= 1) {
        s  += __shfl_down(s,  off, 64);
        ss += __shfl_down(ss, off, 64);
    }
    __shared__ float red0[4], red1[4];
    int lane = threadIdx.x & 63, wid = threadIdx.x >> 6;
    if (lane == 0) { red0[wid] = s; red1[wid] = ss; }
    __syncthreads();
    if (threadIdx.x == 0) {
        float S  = red0[0] + red0[1] + red0[2] + red0[3];
        float SS = red1[0] + red1[1] + red1[2] + red1[3];
        float mu = S / (float)N;
        float var = SS / (float)N - mu * mu;
        stats[bg] = make_float2(mu, rsqrtf(var + EPS));
    }
}

// ---------------- GN pass 2: normalize + transpose -> bf16 hn_t[b][i][c] ----
__global__ __launch_bounds__(256) void gn_apply(
    const float* __restrict__ x, const float2* __restrict__ stats,
    const float* __restrict__ scale, const float* __restrict__ bias,
    unsigned short* __restrict__ hn_t)
{
    __shared__ unsigned short tile[64][72];

    const int b  = blockIdx.z;
    const int c0 = blockIdx.y * 64;
    const int i0 = blockIdx.x * 64;
    const int t  = threadIdx.x;

    const int r = t >> 2;
    const int q = t & 3;
    const int c = c0 + r;

    float2 st = stats[b * G_ + (c >> 4)];
    float scl = scale[c] * st.y;
    float bia = bias[c] - st.x * scl;

    const float* xp = x + ((size_t)b * C_ + c) * HW_ + i0 + q * 16;
#pragma unroll
    for (int u = 0; u < 4; ++u) {
        float4 v = *reinterpret_cast<const float4*>(xp + u * 4);
        int il = q * 16 + u * 4;
        tile[il + 0][r] = f2bf(v.x * scl + bia);
        tile[il + 1][r] = f2bf(v.y * scl + bia);
        tile[il + 2][r] = f2bf(v.z * scl + bia);
        tile[il + 3][r] = f2bf(v.w * scl + bia);
    }
    __syncthreads();

    const int il = t >> 2;
    unsigned short* dst = hn_t + ((size_t)b * HW_ + i0 + il) * C_ + c0;
    *reinterpret_cast<uint4*>(dst + q * 8)        = *reinterpret_cast<uint4*>(&tile[il][q * 8]);
    *reinterpret_cast<uint4*>(dst + (q + 4) * 8)  = *reinterpret_cast<uint4*>(&tile[il][(q + 4) * 8]);
}

// ------- 256x256 NT bf16 MFMA GEMM, 4-deep LDS pipeline + swizzle + vmcnt ---
// C[m][n] = alpha * sum_k A[m*ldA+k] * B[n*ldB+k]  (+bias) (+res)
// BK=32, 512 thr = 8 waves (2Mx4N), wave tile 128x64 = 8x4 16x16x32 frags.
// LDS: 4 buffers x (A 16KB + B 16KB) = 128 KB. Stage tile t+4 after the
// read-closing barrier; steady-state wait = vmcnt(12) (3 tiles in flight).
// Swizzle (involution): phys = logical ^ (((logical>>7)&3)<<4) — spreads the
// 16-consecutive-row ds_read_b128 pattern to ~2-way (free) bank aliasing.
// gload_lds dest stays linear; global SOURCE address is inverse-swizzled.
// BIASMODE: 0 none, 1 per-row bias[m], 2 per-col bias[n].
template<int OUTF32, int BIASMODE, int HASRES>
__global__ __launch_bounds__(512) void gemm_p4(
    const short* __restrict__ A, size_t sA, int ldA,
    const short* __restrict__ Bm, size_t sB, int ldB,
    void* __restrict__ Cm, size_t sC, int ldC,
    const float* __restrict__ bias,
    const float* __restrict__ res, size_t sR,
    int K, float alpha)
{
    __shared__ __align__(16) short lA[4][8192];   // 4 x 16 KB
    __shared__ __align__(16) short lB[4][8192];   // 4 x 16 KB

    const int bz = blockIdx.z;
    const short* Ab = A  + (size_t)bz * sA;
    const short* Bb = Bm + (size_t)bz * sB;

    const int m0 = blockIdx.y * 256;
    const int n0 = blockIdx.x * 256;

    const int t = threadIdx.x;
    const int wv = t >> 6, lane = t & 63;
    const int wm = wv >> 2, wn = wv & 3;          // wave tile: rows wm*128, cols wn*64
    const int fr  = lane & 15;
    const int h16 = (lane >> 4) * 16;             // k-chunk byte offset in row

    // ---- staging precompute: physical LDS dest linear, source pre-swizzled
    size_t sAo[2], sBo[2];
    int pbh[2];
#pragma unroll
    for (int rnd = 0; rnd < 2; ++rnd) {
        int pb = rnd * 8192 + wv * 1024;          // wave-uniform byte base
        int p  = pb + lane * 16;                  // this lane's physical dest
        int a  = p ^ (((p >> 7) & 3) << 4);       // logical offset (involution)
        int row = a >> 6, cs = (a & 63) >> 1;     // row, col in shorts
        sAo[rnd] = (size_t)(m0 + row) * ldA + cs;
        sBo[rnd] = (size_t)(n0 + row) * ldB + cs;
        pbh[rnd] = pb >> 1;                       // dest base in shorts
    }
    auto stage = [&](int buf, int tt) {
        const int k0 = tt * 32;
        gload_lds16(Ab + sAo[0] + k0, &lA[buf][pbh[0]]);
        gload_lds16(Bb + sBo[0] + k0, &lB[buf][pbh[0]]);
        gload_lds16(Ab + sAo[1] + k0, &lA[buf][pbh[1]]);
        gload_lds16(Bb + sBo[1] + k0, &lB[buf][pbh[1]]);
    };

    // ---- fragment ds_read offsets (swizzled), invariant across K
    int aoff[8], boff[4];
#pragma unroll
    for (int fi = 0; fi < 8; ++fi) {
        int ra = wm * 128 + fi * 16 + fr;
        aoff[fi] = (ra * 64 + h16) ^ (((ra >> 1) & 3) << 4);
    }
#pragma unroll
    for (int fj = 0; fj < 4; ++fj) {
        int rb = wn * 64 + fj * 16 + fr;
        boff[fj] = (rb * 64 + h16) ^ (((rb >> 1) & 3) << 4);
    }

    f32x4 zero = {0.f, 0.f, 0.f, 0.f};
    f32x4 acc[8][4];
#pragma unroll
    for (int i = 0; i < 8; ++i)
#pragma unroll
        for (int j = 0; j < 4; ++j) acc[i][j] = zero;

    const int nt = K / 32;

    stage(0, 0); stage(1, 1); stage(2, 2); stage(3, 3);   // 16 loads in flight

    for (int tt = 0; tt < nt; ++tt) {
        const int buf = tt & 3;
        // tile tt landed when <= 4*(tiles-in-flight) newest loads outstanding
        if (tt <= nt - 4)      asm volatile("s_waitcnt vmcnt(12)\n\ts_barrier" ::: "memory");
        else if (tt == nt - 3) asm volatile("s_waitcnt vmcnt(8)\n\ts_barrier" ::: "memory");
        else if (tt == nt - 2) asm volatile("s_waitcnt vmcnt(4)\n\ts_barrier" ::: "memory");
        else                   asm volatile("s_waitcnt vmcnt(0)\n\ts_barrier" ::: "memory");
        __builtin_amdgcn_sched_barrier(0);

        const char* lac = (const char*)&lA[buf][0];
        const char* lbc = (const char*)&lB[buf][0];
        bf16x8 af[8], bf[4];
#pragma unroll
        for (int fi = 0; fi < 8; ++fi) af[fi] = *(const bf16x8*)(lac + aoff[fi]);
#pragma unroll
        for (int fj = 0; fj < 4; ++fj) bf[fj] = *(const bf16x8*)(lbc + boff[fj]);
        asm volatile("s_waitcnt lgkmcnt(0)" ::: "memory");
        __builtin_amdgcn_sched_barrier(0);

        __builtin_amdgcn_s_setprio(1);
#pragma unroll
        for (int fi = 0; fi < 8; ++fi)
#pragma unroll
            for (int fj = 0; fj < 4; ++fj)
                acc[fi][fj] = __builtin_amdgcn_mfma_f32_16x16x32_bf16(af[fi], bf[fj], acc[fi][fj], 0, 0, 0);
        __builtin_amdgcn_s_setprio(0);
        __builtin_amdgcn_sched_barrier(0);

        asm volatile("s_barrier" ::: "memory");   // all waves done reading buf
        if (tt + 4 < nt) stage(buf, tt + 4);      // overwrite is now safe
    }

    // C/D layout: col = lane&15, row = (lane>>4)*4 + reg  [m89-verified]
    const int rq = (lane >> 4) * 4;
#pragma unroll
    for (int fi = 0; fi < 8; ++fi) {
#pragma unroll
        for (int rg = 0; rg < 4; ++rg) {
            int row = m0 + wm * 128 + fi * 16 + rq + rg;
            float bm = (BIASMODE == 1) ? bias[row] : 0.f;
#pragma unroll
            for (int fj = 0; fj < 4; ++fj) {
                int col = n0 + wn * 64 + fj * 16 + fr;
                float vv = acc[fi][fj][rg] * alpha + bm;
                if (BIASMODE == 2) vv += bias[col];
                size_t off = (size_t)row * ldC + col;
                if (HASRES) vv += res[(size_t)bz * sR + off];
                if (OUTF32) ((float*)Cm)[(size_t)bz * sC + off] = vv;
                else ((unsigned short*)Cm)[(size_t)bz * sC + off] = f2bf(vv);
            }
        }
    }
}

// ---------------- in-place bf16 row softmax over 1024 ----------------
__global__ __launch_bounds__(256) void softmax_kernel(unsigned short* __restrict__ attn)
{
    size_t row = blockIdx.x;
    unsigned short* p = attn + row * HW_;
    ushort4 raw = reinterpret_cast<ushort4*>(p)[threadIdx.x];
    float v0 = bf2f(raw.x), v1 = bf2f(raw.y), v2 = bf2f(raw.z), v3 = bf2f(raw.w);

    float mx = fmaxf(fmaxf(v0, v1), fmaxf(v2, v3));
    for (int off = 32; off; off >>= 1) mx = fmaxf(mx, __shfl_down(mx, off, 64));
    __shared__ float redm[4], reds[4];
    int lane = threadIdx.x & 63, wid = threadIdx.x >> 6;
    if (lane == 0) redm[wid] = mx;
    __syncthreads();
    mx = fmaxf(fmaxf(redm[0], redm[1]), fmaxf(redm[2], redm[3]));

    v0 = __expf(v0 - mx); v1 = __expf(v1 - mx);
    v2 = __expf(v2 - mx); v3 = __expf(v3 - mx);
    float sum = v0 + v1 + v2 + v3;
    for (int off = 32; off; off >>= 1) sum += __shfl_down(sum, off, 64);
    if (lane == 0) reds[wid] = sum;
    __syncthreads();
    sum = reds[0] + reds[1] + reds[2] + reds[3];

    float inv = 1.f / sum;
    ushort4 o;
    o.x = f2bf(v0 * inv); o.y = f2bf(v1 * inv);
    o.z = f2bf(v2 * inv); o.w = f2bf(v3 * inv);
    reinterpret_cast<ushort4*>(p)[threadIdx.x] = o;
}

extern "C" void kernel_launch(void* const* d_in, const int* in_sizes, int n_in,
                              void* d_out, int out_size, void* d_ws, size_t ws_size,
                              hipStream_t stream)
{
    const float* x        = (const float*)d_in[0];
    // d_in[1] = temb : unused by the reference
    const float* gn_scale = (const float*)d_in[2];
    const float* gn_bias  = (const float*)d_in[3];
    const float* wq = (const float*)d_in[4];
    const float* bq = (const float*)d_in[5];
    const float* wk = (const float*)d_in[6];
    const float* bk = (const float*)d_in[7];
    const float* wv = (const float*)d_in[8];
    const float* bv = (const float*)d_in[9];
    const float* wo = (const float*)d_in[10];
    const float* bo = (const float*)d_in[11];
    float* out = (float*)d_out;

    // workspace layout (bf16 elements)
    short* ws = (short*)d_ws;
    const size_t E = (size_t)B_ * C_ * HW_;        // 8388608
    short* hn_t = ws;                              // [b][i][c]          E
    short* qk_t = hn_t + E;                        // [b*i][q||k]        2E
    short* v    = qk_t + 2 * E;                    // [b][c][j]          E
    short* ao_t = v + E;                           // [b][i][c]          E
    short* attn = ao_t + E;                        // [b][i][j]          2E
    short* wsq  = attn + 2 * E;                    // wq||wk||wv||wo bf16
    short* wsk  = wsq + (size_t)C_ * C_;
    short* wsv  = wsk + (size_t)C_ * C_;
    short* wso  = wsv + (size_t)C_ * C_;
    float* bqk  = (float*)(wso + (size_t)C_ * C_); // 1024 f32
    float2* stats = (float2*)(bqk + 1024);         // 512 float2

    const float inv_sqrt_c = 0.044194173824159216f;   // 512^-0.5

    f2bf4_kernel<<<dim3(1024), 256, 0, stream>>>(
        wq, wk, wv, wo,
        (unsigned short*)wsq, (unsigned short*)wsk,
        (unsigned short*)wsv, (unsigned short*)wso);
    bias_concat<<<dim3(2), 256, 0, stream>>>(bq, bk, bqk);

    gn_stats<<<dim3(B_ * G_), 256, 0, stream>>>(x, stats);
    gn_apply<<<dim3(HW_ / 64, C_ / 64, B_), 256, 0, stream>>>(
        x, stats, gn_scale, gn_bias, (unsigned short*)hn_t);

    // fused QK projection: qk_t[m][n] = sum_c hn_t[m][c] * (wq||wk)[n][c] + bqk[n]
    dim3 gqk(HW_ / 256, (B_ * HW_) / 256, 1);      // (4, 64, 1)
    gemm_p4<0, 2, 0><<<gqk, 512, 0, stream>>>(
        hn_t, 0, C_, wsq, 0, C_, qk_t, 0, HW_, bqk, nullptr, 0, C_, 1.0f);

    // v[c][j] = sum_k wv[c][k] * hn_t[j][k] + bv[c]
    dim3 gv(HW_ / 256, C_ / 256, B_);              // (4, 2, 16)
    gemm_p4<0, 1, 0><<<gv, 512, 0, stream>>>(
        wsv, 0, C_, hn_t, CHW, C_, v, CHW, HW_, bv, nullptr, 0, C_, 1.0f);

    // attn[i][j] = (sum_c q[i][c] * k[j][c]) * C^-0.5   (q,k inside qk_t)
    dim3 gs(HW_ / 256, HW_ / 256, B_);             // (4, 4, 16)
    gemm_p4<0, 0, 0><<<gs, 512, 0, stream>>>(
        qk_t, HW2, HW_, qk_t + C_, HW2, HW_, attn, HW2, HW_,
        nullptr, nullptr, 0, C_, inv_sqrt_c);

    softmax_kernel<<<dim3(B_ * HW_), 256, 0, stream>>>((unsigned short*)attn);

    // ao_t[i][c] = sum_j attn[i][j] * v[c][j]
    dim3 gp(C_ / 256, HW_ / 256, B_);              // (2, 4, 16)
    gemm_p4<0, 0, 0><<<gp, 512, 0, stream>>>(
        attn, HW2, HW_, v, CHW, HW_, ao_t, CHW, C_, nullptr, nullptr, 0, HW_, 1.0f);

    // out[c][i] = x + sum_k wo[c][k] * ao_t[i][k] + bo[c]
    dim3 go(HW_ / 256, C_ / 256, B_);              // (4, 2, 16)
    gemm_p4<1, 1, 1><<<go, 512, 0, stream>>>(
        wso, 0, C_, ao_t, CHW, C_, out, CHW, HW_, bo, x, CHW, C_, 1.0f);
}

// Round 6
// 172.642 us; speedup vs baseline: 1.1670x; 1.1670x over previous
//
#include <hip/hip_runtime.h>

#define B_   16
#define C_   512
#define HW_  1024
#define G_   32
#define CPG  16
#define EPS  1e-5f
#define CHW  ((size_t)C_ * HW_)        // 524288 elements per batch (c,hw)
#define HW2  ((size_t)HW_ * HW_)       // 1048576 elements per batch (hw,hw)

typedef __attribute__((ext_vector_type(8))) short bf16x8;
typedef __attribute__((ext_vector_type(4))) float f32x4;

__device__ inline unsigned short f2bf(float f) {
    union { float f; unsigned u; } v; v.f = f;
    unsigned r = v.u + 0x7fffu + ((v.u >> 16) & 1u);   // RNE
    return (unsigned short)(r >> 16);
}
__device__ inline float bf2f(unsigned short h) {
    union { unsigned u; float f; } v; v.u = (unsigned)h << 16;
    return v.f;
}

__device__ inline void gload_lds16(const void* g, void* lds) {
    __builtin_amdgcn_global_load_lds(
        (const __attribute__((address_space(1))) void*)g,
        (__attribute__((address_space(3))) void*)lds,
        16, 0, 0);
}

// ---------------- fp32 -> bf16 weight convert (all 4 weights, one launch) ----
__global__ __launch_bounds__(256) void f2bf4_kernel(
    const float* __restrict__ w0, const float* __restrict__ w1,
    const float* __restrict__ w2, const float* __restrict__ w3,
    unsigned short* __restrict__ o0, unsigned short* __restrict__ o1,
    unsigned short* __restrict__ o2, unsigned short* __restrict__ o3)
{
    int wsel = blockIdx.x >> 8;
    int blk  = blockIdx.x & 255;
    const float* in = (wsel == 0) ? w0 : (wsel == 1) ? w1 : (wsel == 2) ? w2 : w3;
    unsigned short* out = (wsel == 0) ? o0 : (wsel == 1) ? o1 : (wsel == 2) ? o2 : o3;
    int i = (blk * 256 + threadIdx.x) * 4;
    float4 f = *reinterpret_cast<const float4*>(in + i);
    ushort4 o;
    o.x = f2bf(f.x); o.y = f2bf(f.y); o.z = f2bf(f.z); o.w = f2bf(f.w);
    *reinterpret_cast<ushort4*>(out + i) = o;
}

// ---------------- concat bq||bk -> bqk[1024] ----------------
__global__ __launch_bounds__(256) void bias_concat(
    const float* __restrict__ bq, const float* __restrict__ bk,
    float* __restrict__ bqk)
{
    const float* src = blockIdx.x ? bk : bq;
    bqk[blockIdx.x * 512 + threadIdx.x]       = src[threadIdx.x];
    bqk[blockIdx.x * 512 + 256 + threadIdx.x] = src[256 + threadIdx.x];
}

// ---------------- GN pass 1: per-(b,g) mean / rsqrt(var) ----------------
__global__ __launch_bounds__(256) void gn_stats(const float* __restrict__ x,
                                                float2* __restrict__ stats)
{
    int bg = blockIdx.x;                                  // 0..511
    const float4* xp = reinterpret_cast<const float4*>(x + (size_t)bg * CPG * HW_);
    const int N = CPG * HW_;                              // 16384

    float s = 0.f, ss = 0.f;
#pragma unroll
    for (int k = 0; k < 16; ++k) {
        float4 v = xp[threadIdx.x + k * 256];
        s  += v.x + v.y + v.z + v.w;
        ss += v.x * v.x + v.y * v.y + v.z * v.z + v.w * v.w;
    }
    for (int off = 32; off; off >>= 1) {
        s  += __shfl_down(s,  off, 64);
        ss += __shfl_down(ss, off, 64);
    }
    __shared__ float red0[4], red1[4];
    int lane = threadIdx.x & 63, wid = threadIdx.x >> 6;
    if (lane == 0) { red0[wid] = s; red1[wid] = ss; }
    __syncthreads();
    if (threadIdx.x == 0) {
        float S  = red0[0] + red0[1] + red0[2] + red0[3];
        float SS = red1[0] + red1[1] + red1[2] + red1[3];
        float mu = S / (float)N;
        float var = SS / (float)N - mu * mu;
        stats[bg] = make_float2(mu, rsqrtf(var + EPS));
    }
}

// ---------------- GN pass 2: normalize + transpose -> bf16 hn_t[b][i][c] ----
__global__ __launch_bounds__(256) void gn_apply(
    const float* __restrict__ x, const float2* __restrict__ stats,
    const float* __restrict__ scale, const float* __restrict__ bias,
    unsigned short* __restrict__ hn_t)
{
    __shared__ unsigned short tile[64][72];

    const int b  = blockIdx.z;
    const int c0 = blockIdx.y * 64;
    const int i0 = blockIdx.x * 64;
    const int t  = threadIdx.x;

    const int r = t >> 2;
    const int q = t & 3;
    const int c = c0 + r;

    float2 st = stats[b * G_ + (c >> 4)];
    float scl = scale[c] * st.y;
    float bia = bias[c] - st.x * scl;

    const float* xp = x + ((size_t)b * C_ + c) * HW_ + i0 + q * 16;
#pragma unroll
    for (int u = 0; u < 4; ++u) {
        float4 v = *reinterpret_cast<const float4*>(xp + u * 4);
        int il = q * 16 + u * 4;
        tile[il + 0][r] = f2bf(v.x * scl + bia);
        tile[il + 1][r] = f2bf(v.y * scl + bia);
        tile[il + 2][r] = f2bf(v.z * scl + bia);
        tile[il + 3][r] = f2bf(v.w * scl + bia);
    }
    __syncthreads();

    const int il = t >> 2;
    unsigned short* dst = hn_t + ((size_t)b * HW_ + i0 + il) * C_ + c0;
    *reinterpret_cast<uint4*>(dst + q * 8)        = *reinterpret_cast<uint4*>(&tile[il][q * 8]);
    *reinterpret_cast<uint4*>(dst + (q + 4) * 8)  = *reinterpret_cast<uint4*>(&tile[il][(q + 4) * 8]);
}

// ---- 128x128 NT bf16 MFMA GEMM: 3-buffer LDS pipeline, swizzle, counted vmcnt
// C[m][n] = alpha * sum_k A[m*ldA+k] * B[n*ldB+k]  (+bias) (+res)
// BK=32, 256 thr = 4 waves (2x2), wave tile 64x64 = 4x4 16x16x32 frags.
// LDS: 3 buffers x (A 8KB + B 8KB) = 48 KB -> 3 blocks/CU, 12 waves/CU.
// Pipeline: prologue stages tiles 0..2; steady state waits vmcnt(8) (2 tiles
// in flight), stages tile tt+3 after the read-closing barrier. No explicit
// lgkmcnt in the compute region: the compiler interleaves ds_read/MFMA with
// fine-grained lgkmcnt(N) (m97 behavior); asm memory clobbers pin the phase
// edges only.
// Swizzle (involution, round-5-verified conflict-free): phys = logical ^
// (((logical>>7)&3)<<4). gload_lds dest linear; SOURCE pre-swizzled; ds_read
// offsets swizzled.
// BIASMODE: 0 none, 1 per-row bias[m], 2 per-col bias[n].
template<int OUTF32, int BIASMODE, int HASRES>
__global__ __launch_bounds__(256) void gemm_3b(
    const short* __restrict__ A, size_t sA, int ldA,
    const short* __restrict__ Bm, size_t sB, int ldB,
    void* __restrict__ Cm, size_t sC, int ldC,
    const float* __restrict__ bias,
    const float* __restrict__ res, size_t sR,
    int K, float alpha)
{
    __shared__ __align__(16) short lA[3][4096];   // 3 x 8 KB
    __shared__ __align__(16) short lB[3][4096];   // 3 x 8 KB

    const int bz = blockIdx.z;
    const short* Ab = A  + (size_t)bz * sA;
    const short* Bb = Bm + (size_t)bz * sB;

    const int m0 = blockIdx.y * 128;
    const int n0 = blockIdx.x * 128;

    const int t = threadIdx.x;
    const int wv = t >> 6, lane = t & 63;
    const int wrow = (wv >> 1) * 64, wcol = (wv & 1) * 64;
    const int fr  = lane & 15;
    const int h16 = (lane >> 4) * 16;             // k-chunk byte offset in row

    // staging: 2 chunks of 16 rows per wave; dest linear, source pre-swizzled
    size_t sAo[2], sBo[2];
    int pbh[2];
#pragma unroll
    for (int rnd = 0; rnd < 2; ++rnd) {
        int pb = (2 * wv + rnd) * 1024;           // wave-uniform byte base
        int p  = pb + lane * 16;                  // lane's physical dest byte
        int a  = p ^ (((p >> 7) & 3) << 4);       // logical byte (involution)
        int row = a >> 6, cs = (a & 63) >> 1;
        sAo[rnd] = (size_t)(m0 + row) * ldA + cs;
        sBo[rnd] = (size_t)(n0 + row) * ldB + cs;
        pbh[rnd] = pb >> 1;
    }
    auto stage = [&](int buf, int tt) {
        const int k0 = tt * 32;
        gload_lds16(Ab + sAo[0] + k0, &lA[buf][pbh[0]]);
        gload_lds16(Bb + sBo[0] + k0, &lB[buf][pbh[0]]);
        gload_lds16(Ab + sAo[1] + k0, &lA[buf][pbh[1]]);
        gload_lds16(Bb + sBo[1] + k0, &lB[buf][pbh[1]]);
    };

    // fragment ds_read byte offsets (swizzled), invariant across K
    int aoff[4], boff[4];
#pragma unroll
    for (int fi = 0; fi < 4; ++fi) {
        int ra = wrow + fi * 16 + fr;
        aoff[fi] = (ra * 64 + h16) ^ (((ra >> 1) & 3) << 4);
    }
#pragma unroll
    for (int fj = 0; fj < 4; ++fj) {
        int rb = wcol + fj * 16 + fr;
        boff[fj] = (rb * 64 + h16) ^ (((rb >> 1) & 3) << 4);
    }

    f32x4 zero = {0.f, 0.f, 0.f, 0.f};
    f32x4 acc[4][4];
#pragma unroll
    for (int i = 0; i < 4; ++i)
#pragma unroll
        for (int j = 0; j < 4; ++j) acc[i][j] = zero;

    const int nt = K / 32;

    stage(0, 0); stage(1, 1); stage(2, 2);        // 12 loads in flight

    int buf = 0;
    for (int tt = 0; tt < nt; ++tt) {
        // open: tile tt landed (own loads); barrier syncs other waves' chunks
        if (tt + 2 < nt)      asm volatile("s_waitcnt vmcnt(8)\n\ts_barrier" ::: "memory");
        else if (tt + 1 < nt) asm volatile("s_waitcnt vmcnt(4)\n\ts_barrier" ::: "memory");
        else                  asm volatile("s_waitcnt vmcnt(0)\n\ts_barrier" ::: "memory");

        const char* lac = (const char*)&lA[buf][0];
        const char* lbc = (const char*)&lB[buf][0];
        bf16x8 af[4], bfv[4];
#pragma unroll
        for (int fi = 0; fi < 4; ++fi) af[fi] = *(const bf16x8*)(lac + aoff[fi]);
#pragma unroll
        for (int fj = 0; fj < 4; ++fj) bfv[fj] = *(const bf16x8*)(lbc + boff[fj]);
#pragma unroll
        for (int i = 0; i < 4; ++i)
#pragma unroll
            for (int j = 0; j < 4; ++j)
                acc[i][j] = __builtin_amdgcn_mfma_f32_16x16x32_bf16(af[i], bfv[j], acc[i][j], 0, 0, 0);

        // close: every ds_read above was consumed by an MFMA (compiler waits),
        // so reads of buf are complete; after barrier it is safe to overwrite.
        asm volatile("s_barrier" ::: "memory");
        if (tt + 3 < nt) stage(buf, tt + 3);
        buf = (buf == 2) ? 0 : buf + 1;
    }

    // C/D layout: col = lane&15, row = (lane>>4)*4 + reg  [m89-verified]
    const int rq = (lane >> 4) * 4;
#pragma unroll
    for (int fi = 0; fi < 4; ++fi) {
#pragma unroll
        for (int rg = 0; rg < 4; ++rg) {
            int row = m0 + wrow + fi * 16 + rq + rg;
            float bm = (BIASMODE == 1) ? bias[row] : 0.f;
#pragma unroll
            for (int fj = 0; fj < 4; ++fj) {
                int col = n0 + wcol + fj * 16 + fr;
                float vv = acc[fi][fj][rg] * alpha + bm;
                if (BIASMODE == 2) vv += bias[col];
                size_t off = (size_t)row * ldC + col;
                if (HASRES) vv += res[(size_t)bz * sR + off];
                if (OUTF32) ((float*)Cm)[(size_t)bz * sC + off] = vv;
                else ((unsigned short*)Cm)[(size_t)bz * sC + off] = f2bf(vv);
            }
        }
    }
}

// ---------------- in-place bf16 row softmax over 1024 ----------------
__global__ __launch_bounds__(256) void softmax_kernel(unsigned short* __restrict__ attn)
{
    size_t row = blockIdx.x;
    unsigned short* p = attn + row * HW_;
    ushort4 raw = reinterpret_cast<ushort4*>(p)[threadIdx.x];
    float v0 = bf2f(raw.x), v1 = bf2f(raw.y), v2 = bf2f(raw.z), v3 = bf2f(raw.w);

    float mx = fmaxf(fmaxf(v0, v1), fmaxf(v2, v3));
    for (int off = 32; off; off >>= 1) mx = fmaxf(mx, __shfl_down(mx, off, 64));
    __shared__ float redm[4], reds[4];
    int lane = threadIdx.x & 63, wid = threadIdx.x >> 6;
    if (lane == 0) redm[wid] = mx;
    __syncthreads();
    mx = fmaxf(fmaxf(redm[0], redm[1]), fmaxf(redm[2], redm[3]));

    v0 = __expf(v0 - mx); v1 = __expf(v1 - mx);
    v2 = __expf(v2 - mx); v3 = __expf(v3 - mx);
    float sum = v0 + v1 + v2 + v3;
    for (int off = 32; off; off >>= 1) sum += __shfl_down(sum, off, 64);
    if (lane == 0) reds[wid] = sum;
    __syncthreads();
    sum = reds[0] + reds[1] + reds[2] + reds[3];

    float inv = 1.f / sum;
    ushort4 o;
    o.x = f2bf(v0 * inv); o.y = f2bf(v1 * inv);
    o.z = f2bf(v2 * inv); o.w = f2bf(v3 * inv);
    reinterpret_cast<ushort4*>(p)[threadIdx.x] = o;
}

extern "C" void kernel_launch(void* const* d_in, const int* in_sizes, int n_in,
                              void* d_out, int out_size, void* d_ws, size_t ws_size,
                              hipStream_t stream)
{
    const float* x        = (const float*)d_in[0];
    // d_in[1] = temb : unused by the reference
    const float* gn_scale = (const float*)d_in[2];
    const float* gn_bias  = (const float*)d_in[3];
    const float* wq = (const float*)d_in[4];
    const float* bq = (const float*)d_in[5];
    const float* wk = (const float*)d_in[6];
    const float* bk = (const float*)d_in[7];
    const float* wv = (const float*)d_in[8];
    const float* bv = (const float*)d_in[9];
    const float* wo = (const float*)d_in[10];
    const float* bo = (const float*)d_in[11];
    float* out = (float*)d_out;

    // workspace layout (bf16 elements)
    short* ws = (short*)d_ws;
    const size_t E = (size_t)B_ * C_ * HW_;        // 8388608
    short* hn_t = ws;                              // [b][i][c]          E
    short* qk_t = hn_t + E;                        // [b*i][q||k]        2E
    short* v    = qk_t + 2 * E;                    // [b][c][j]          E
    short* ao_t = v + E;                           // [b][i][c]          E
    short* attn = ao_t + E;                        // [b][i][j]          2E
    short* wsq  = attn + 2 * E;                    // wq||wk||wv||wo bf16
    short* wsk  = wsq + (size_t)C_ * C_;
    short* wsv  = wsk + (size_t)C_ * C_;
    short* wso  = wsv + (size_t)C_ * C_;
    float* bqk  = (float*)(wso + (size_t)C_ * C_); // 1024 f32
    float2* stats = (float2*)(bqk + 1024);         // 512 float2

    const float inv_sqrt_c = 0.044194173824159216f;   // 512^-0.5

    f2bf4_kernel<<<dim3(1024), 256, 0, stream>>>(
        wq, wk, wv, wo,
        (unsigned short*)wsq, (unsigned short*)wsk,
        (unsigned short*)wsv, (unsigned short*)wso);
    bias_concat<<<dim3(2), 256, 0, stream>>>(bq, bk, bqk);

    gn_stats<<<dim3(B_ * G_), 256, 0, stream>>>(x, stats);
    gn_apply<<<dim3(HW_ / 64, C_ / 64, B_), 256, 0, stream>>>(
        x, stats, gn_scale, gn_bias, (unsigned short*)hn_t);

    // fused QK projection: qk_t[m][n] = sum_c hn_t[m][c] * (wq||wk)[n][c] + bqk[n]
    dim3 gqk(HW_ / 128, (B_ * HW_) / 128, 1);      // (8, 128, 1)
    gemm_3b<0, 2, 0><<<gqk, 256, 0, stream>>>(
        hn_t, 0, C_, wsq, 0, C_, qk_t, 0, HW_, bqk, nullptr, 0, C_, 1.0f);

    // v[c][j] = sum_k wv[c][k] * hn_t[j][k] + bv[c]
    dim3 gv(HW_ / 128, C_ / 128, B_);              // (8, 4, 16)
    gemm_3b<0, 1, 0><<<gv, 256, 0, stream>>>(
        wsv, 0, C_, hn_t, CHW, C_, v, CHW, HW_, bv, nullptr, 0, C_, 1.0f);

    // attn[i][j] = (sum_c q[i][c] * k[j][c]) * C^-0.5   (q,k inside qk_t)
    dim3 gs(HW_ / 128, HW_ / 128, B_);             // (8, 8, 16)
    gemm_3b<0, 0, 0><<<gs, 256, 0, stream>>>(
        qk_t, HW2, HW_, qk_t + C_, HW2, HW_, attn, HW2, HW_,
        nullptr, nullptr, 0, C_, inv_sqrt_c);

    softmax_kernel<<<dim3(B_ * HW_), 256, 0, stream>>>((unsigned short*)attn);

    // ao_t[i][c] = sum_j attn[i][j] * v[c][j]
    dim3 gp(C_ / 128, HW_ / 128, B_);              // (4, 8, 16)
    gemm_3b<0, 0, 0><<<gp, 256, 0, stream>>>(
        attn, HW2, HW_, v, CHW, HW_, ao_t, CHW, C_, nullptr, nullptr, 0, HW_, 1.0f);

    // out[c][i] = x + sum_k wo[c][k] * ao_t[i][k] + bo[c]
    dim3 go(HW_ / 128, C_ / 128, B_);              // (8, 4, 16)
    gemm_3b<1, 1, 1><<<go, 256, 0, stream>>>(
        wso, 0, C_, ao_t, CHW, C_, out, CHW, HW_, bo, x, CHW, C_, 1.0f);
}

// Round 7
// 170.132 us; speedup vs baseline: 1.1842x; 1.0148x over previous
//
#include <hip/hip_runtime.h>

#define B_   16
#define C_   512
#define HW_  1024
#define G_   32
#define CPG  16
#define EPS  1e-5f
#define CHW  ((size_t)C_ * HW_)        // 524288 elements per batch (c,hw)
#define HW2  ((size_t)HW_ * HW_)       // 1048576 elements per batch (hw,hw)

typedef __attribute__((ext_vector_type(8))) short bf16x8;
typedef __attribute__((ext_vector_type(4))) float f32x4;

__device__ inline unsigned short f2bf(float f) {
    union { float f; unsigned u; } v; v.f = f;
    unsigned r = v.u + 0x7fffu + ((v.u >> 16) & 1u);   // RNE
    return (unsigned short)(r >> 16);
}
__device__ inline float bf2f(unsigned short h) {
    union { unsigned u; float f; } v; v.u = (unsigned)h << 16;
    return v.f;
}

__device__ inline void gload_lds16(const void* g, void* lds) {
    __builtin_amdgcn_global_load_lds(
        (const __attribute__((address_space(1))) void*)g,
        (__attribute__((address_space(3))) void*)lds,
        16, 0, 0);
}

// ---------------- fp32 -> bf16 weight convert (all 4 weights, one launch) ----
__global__ __launch_bounds__(256) void f2bf4_kernel(
    const float* __restrict__ w0, const float* __restrict__ w1,
    const float* __restrict__ w2, const float* __restrict__ w3,
    unsigned short* __restrict__ o0, unsigned short* __restrict__ o1,
    unsigned short* __restrict__ o2, unsigned short* __restrict__ o3)
{
    int wsel = blockIdx.x >> 8;
    int blk  = blockIdx.x & 255;
    const float* in = (wsel == 0) ? w0 : (wsel == 1) ? w1 : (wsel == 2) ? w2 : w3;
    unsigned short* out = (wsel == 0) ? o0 : (wsel == 1) ? o1 : (wsel == 2) ? o2 : o3;
    int i = (blk * 256 + threadIdx.x) * 4;
    float4 f = *reinterpret_cast<const float4*>(in + i);
    ushort4 o;
    o.x = f2bf(f.x); o.y = f2bf(f.y); o.z = f2bf(f.z); o.w = f2bf(f.w);
    *reinterpret_cast<ushort4*>(out + i) = o;
}

// ---------------- concat bq||bk -> bqk[1024] ----------------
__global__ __launch_bounds__(256) void bias_concat(
    const float* __restrict__ bq, const float* __restrict__ bk,
    float* __restrict__ bqk)
{
    const float* src = blockIdx.x ? bk : bq;
    bqk[blockIdx.x * 512 + threadIdx.x]       = src[threadIdx.x];
    bqk[blockIdx.x * 512 + 256 + threadIdx.x] = src[256 + threadIdx.x];
}

// ---------------- GN pass 1: per-(b,g) mean / rsqrt(var) ----------------
__global__ __launch_bounds__(256) void gn_stats(const float* __restrict__ x,
                                                float2* __restrict__ stats)
{
    int bg = blockIdx.x;                                  // 0..511
    const float4* xp = reinterpret_cast<const float4*>(x + (size_t)bg * CPG * HW_);
    const int N = CPG * HW_;                              // 16384

    float s = 0.f, ss = 0.f;
#pragma unroll
    for (int k = 0; k < 16; ++k) {
        float4 v = xp[threadIdx.x + k * 256];
        s  += v.x + v.y + v.z + v.w;
        ss += v.x * v.x + v.y * v.y + v.z * v.z + v.w * v.w;
    }
    for (int off = 32; off; off >>= 1) {
        s  += __shfl_down(s,  off, 64);
        ss += __shfl_down(ss, off, 64);
    }
    __shared__ float red0[4], red1[4];
    int lane = threadIdx.x & 63, wid = threadIdx.x >> 6;
    if (lane == 0) { red0[wid] = s; red1[wid] = ss; }
    __syncthreads();
    if (threadIdx.x == 0) {
        float S  = red0[0] + red0[1] + red0[2] + red0[3];
        float SS = red1[0] + red1[1] + red1[2] + red1[3];
        float mu = S / (float)N;
        float var = SS / (float)N - mu * mu;
        stats[bg] = make_float2(mu, rsqrtf(var + EPS));
    }
}

// ---------------- GN pass 2: normalize + transpose -> bf16 hn_t[b][i][c] ----
__global__ __launch_bounds__(256) void gn_apply(
    const float* __restrict__ x, const float2* __restrict__ stats,
    const float* __restrict__ scale, const float* __restrict__ bias,
    unsigned short* __restrict__ hn_t)
{
    __shared__ unsigned short tile[64][72];

    const int b  = blockIdx.z;
    const int c0 = blockIdx.y * 64;
    const int i0 = blockIdx.x * 64;
    const int t  = threadIdx.x;

    const int r = t >> 2;
    const int q = t & 3;
    const int c = c0 + r;

    float2 st = stats[b * G_ + (c >> 4)];
    float scl = scale[c] * st.y;
    float bia = bias[c] - st.x * scl;

    const float* xp = x + ((size_t)b * C_ + c) * HW_ + i0 + q * 16;
#pragma unroll
    for (int u = 0; u < 4; ++u) {
        float4 v = *reinterpret_cast<const float4*>(xp + u * 4);
        int il = q * 16 + u * 4;
        tile[il + 0][r] = f2bf(v.x * scl + bia);
        tile[il + 1][r] = f2bf(v.y * scl + bia);
        tile[il + 2][r] = f2bf(v.z * scl + bia);
        tile[il + 3][r] = f2bf(v.w * scl + bia);
    }
    __syncthreads();

    const int il = t >> 2;
    unsigned short* dst = hn_t + ((size_t)b * HW_ + i0 + il) * C_ + c0;
    *reinterpret_cast<uint4*>(dst + q * 8)        = *reinterpret_cast<uint4*>(&tile[il][q * 8]);
    *reinterpret_cast<uint4*>(dst + (q + 4) * 8)  = *reinterpret_cast<uint4*>(&tile[il][(q + 4) * 8]);
}

// ================= 256x128 NT bf16 MFMA GEMM, 8-phase pipeline ==============
// C[m][n] = alpha * sum_k A[m*ldA+k] * B[n*ldB+k]  (+bias) (+res)
// BM=256, BN=128, BK=64. 512 thr = 8 waves (4M x 2N), wave tile 64x64
// (acc 4x4 frags of 16x16x32). LDS sliced by K-HALF slots:
//   A[par][kh]: 256 rows x 32k = 16 KB  (4 slots, bytes 0..65535)
//   B[par][kh]: 128 rows x 32k =  8 KB  (4 slots, bytes 65536..98303)
// Per K-tile 4 phases (ks = k-step, jh = fj-half):
//   ph0 (ks0,jh0): [vmcnt(6)+bar] read af0-3+bf01, stage A(kt+1)k1, 8 MFMA
//   ph1 (ks0,jh1): read bf23, stage B(kt+1)k1, 8 MFMA, [lgkm0+bar]
//   ph2 (ks1,jh0): [vmcnt(6)+bar] read af+bf, stage A(kt+2)k0, 8 MFMA
//   ph3 (ks1,jh1): read bf, stage B(kt+2)k0, 8 MFMA, [lgkm0+bar]
// Slot-death proof: Ak0 read ph0 only -> staged ph2; Bk0 read ph0-1 -> ph3;
// Ak1/Bk1 (other parity) read kt-1.ph2/3 -> staged kt.ph0/1. Every overwrite
// is separated from the last read by >=1 lgkmcnt(0)+barrier.
// vmcnt: steady 6 (1.5 tiles in flight); tail 3 then 0. Never drained mid-loop.
// Swizzle (involution, r5/r6-verified): off ^= ((off>>7)&3)<<4 within slot;
// gload_lds dest linear, global SOURCE pre-swizzled, ds_read offsets swizzled.
// BIASMODE: 0 none, 1 per-row bias[m], 2 per-col bias[n].
template<int OUTF32, int BIASMODE, int HASRES>
__global__ __launch_bounds__(512) void gemm_8p(
    const short* __restrict__ A, size_t sA, int ldA,
    const short* __restrict__ Bm, size_t sB, int ldB,
    void* __restrict__ Cm, size_t sC, int ldC,
    const float* __restrict__ bias,
    const float* __restrict__ res, size_t sR,
    int K, float alpha)
{
    __shared__ __align__(16) short lds[49152];    // 96 KB

    const int bz = blockIdx.z;
    const short* Ab = A  + (size_t)bz * sA;
    const short* Bb = Bm + (size_t)bz * sB;
    const int m0 = blockIdx.y * 256;
    const int n0 = blockIdx.x * 128;

    const int t = threadIdx.x;
    const int wv = t >> 6, lane = t & 63;
    const int wm = wv >> 1, wn = wv & 1;          // 4 M-waves x 2 N-waves
    const int fr = lane & 15;
    const int cb = (lane >> 4) * 16;              // 16B k-chunk byte offset

    // ---- staging: source element offsets (pre-swizzled), dest linear
    size_t srcA0, srcA1, srcB;
    {
        int p0 = t * 16;
        int a0 = p0 ^ (((p0 >> 7) & 3) << 4);
        srcA0 = (size_t)(m0 + (a0 >> 6)) * ldA + ((a0 & 63) >> 1);
        int p1 = 8192 + t * 16;
        int a1 = p1 ^ (((p1 >> 7) & 3) << 4);
        srcA1 = (size_t)(m0 + (a1 >> 6)) * ldA + ((a1 & 63) >> 1);
        srcB  = (size_t)(n0 + (a0 >> 6)) * ldB + ((a0 & 63) >> 1);  // 128 rows: a0>>6 < 128 for p0<8192
    }
    auto stageA = [&](int par, int kh, int kt_src) {
        const short* s = Ab + kt_src * 64 + kh * 32;
        short* d = &lds[(par * 2 + kh) * 8192 + wv * 512];
        gload_lds16(s + srcA0, d);
        gload_lds16(s + srcA1, d + 4096);
    };
    auto stageB = [&](int par, int kh, int kt_src) {
        const short* s = Bb + kt_src * 64 + kh * 32;
        gload_lds16(s + srcB, &lds[32768 + (par * 2 + kh) * 4096 + wv * 512]);
    };

    // ---- fragment ds_read byte offsets within slot (swizzled), K-invariant
    int aoffs[4], boffs[4];
#pragma unroll
    for (int fi = 0; fi < 4; ++fi) {
        int row = wm * 64 + fi * 16 + fr;         // 0..255
        int off = row * 64 + cb;
        aoffs[fi] = off ^ (((off >> 7) & 3) << 4);
    }
#pragma unroll
    for (int fj = 0; fj < 4; ++fj) {
        int row = wn * 64 + fj * 16 + fr;         // 0..127
        int off = row * 64 + cb;
        boffs[fj] = off ^ (((off >> 7) & 3) << 4);
    }

    f32x4 acc[4][4];
#pragma unroll
    for (int i = 0; i < 4; ++i)
#pragma unroll
        for (int j = 0; j < 4; ++j) acc[i][j] = (f32x4){0.f, 0.f, 0.f, 0.f};

    const int NT = K >> 6;
    const char* L = (const char*)lds;

    // prologue: 9 per-thread loads, ordered to match steady-state cadence
    stageA(0, 0, 0); stageB(0, 0, 0);
    stageA(0, 1, 0); stageB(0, 1, 0);
    stageA(1, 0, 1); stageB(1, 0, 1);

    for (int kt = 0; kt < NT; ++kt) {
        const int par = kt & 1;
        const int AB0 = (par * 2) * 16384;        // byte bases
        const int AB1 = AB0 + 16384;
        const int BB0 = 65536 + (par * 2) * 8192;
        const int BB1 = BB0 + 8192;

        bf16x8 af0, af1, af2, af3, bf0, bf1;

        // ---------- phase 0: ks=0, fj 0-1 ----------
        if (kt == NT - 1) asm volatile("s_waitcnt vmcnt(3)\n\ts_barrier" ::: "memory");
        else              asm volatile("s_waitcnt vmcnt(6)\n\ts_barrier" ::: "memory");
        af0 = *(const bf16x8*)(L + AB0 + aoffs[0]);
        af1 = *(const bf16x8*)(L + AB0 + aoffs[1]);
        af2 = *(const bf16x8*)(L + AB0 + aoffs[2]);
        af3 = *(const bf16x8*)(L + AB0 + aoffs[3]);
        bf0 = *(const bf16x8*)(L + BB0 + boffs[0]);
        bf1 = *(const bf16x8*)(L + BB0 + boffs[1]);
        if (kt + 1 < NT) stageA(par ^ 1, 1, kt + 1);
        __builtin_amdgcn_s_setprio(1);
        acc[0][0] = __builtin_amdgcn_mfma_f32_16x16x32_bf16(af0, bf0, acc[0][0], 0, 0, 0);
        acc[1][0] = __builtin_amdgcn_mfma_f32_16x16x32_bf16(af1, bf0, acc[1][0], 0, 0, 0);
        acc[2][0] = __builtin_amdgcn_mfma_f32_16x16x32_bf16(af2, bf0, acc[2][0], 0, 0, 0);
        acc[3][0] = __builtin_amdgcn_mfma_f32_16x16x32_bf16(af3, bf0, acc[3][0], 0, 0, 0);
        acc[0][1] = __builtin_amdgcn_mfma_f32_16x16x32_bf16(af0, bf1, acc[0][1], 0, 0, 0);
        acc[1][1] = __builtin_amdgcn_mfma_f32_16x16x32_bf16(af1, bf1, acc[1][1], 0, 0, 0);
        acc[2][1] = __builtin_amdgcn_mfma_f32_16x16x32_bf16(af2, bf1, acc[2][1], 0, 0, 0);
        acc[3][1] = __builtin_amdgcn_mfma_f32_16x16x32_bf16(af3, bf1, acc[3][1], 0, 0, 0);
        __builtin_amdgcn_s_setprio(0);
        asm volatile("s_waitcnt lgkmcnt(0)\n\ts_barrier" ::: "memory");

        // ---------- phase 1: ks=0, fj 2-3 ----------
        bf0 = *(const bf16x8*)(L + BB0 + boffs[2]);
        bf1 = *(const bf16x8*)(L + BB0 + boffs[3]);
        if (kt + 1 < NT) stageB(par ^ 1, 1, kt + 1);
        __builtin_amdgcn_s_setprio(1);
        acc[0][2] = __builtin_amdgcn_mfma_f32_16x16x32_bf16(af0, bf0, acc[0][2], 0, 0, 0);
        acc[1][2] = __builtin_amdgcn_mfma_f32_16x16x32_bf16(af1, bf0, acc[1][2], 0, 0, 0);
        acc[2][2] = __builtin_amdgcn_mfma_f32_16x16x32_bf16(af2, bf0, acc[2][2], 0, 0, 0);
        acc[3][2] = __builtin_amdgcn_mfma_f32_16x16x32_bf16(af3, bf0, acc[3][2], 0, 0, 0);
        acc[0][3] = __builtin_amdgcn_mfma_f32_16x16x32_bf16(af0, bf1, acc[0][3], 0, 0, 0);
        acc[1][3] = __builtin_amdgcn_mfma_f32_16x16x32_bf16(af1, bf1, acc[1][3], 0, 0, 0);
        acc[2][3] = __builtin_amdgcn_mfma_f32_16x16x32_bf16(af2, bf1, acc[2][3], 0, 0, 0);
        acc[3][3] = __builtin_amdgcn_mfma_f32_16x16x32_bf16(af3, bf1, acc[3][3], 0, 0, 0);
        __builtin_amdgcn_s_setprio(0);
        asm volatile("s_waitcnt lgkmcnt(0)\n\ts_barrier" ::: "memory");

        // ---------- phase 2: ks=1, fj 0-1 ----------
        if (kt == NT - 1) asm volatile("s_waitcnt vmcnt(0)\n\ts_barrier" ::: "memory");
        else              asm volatile("s_waitcnt vmcnt(6)\n\ts_barrier" ::: "memory");
        af0 = *(const bf16x8*)(L + AB1 + aoffs[0]);
        af1 = *(const bf16x8*)(L + AB1 + aoffs[1]);
        af2 = *(const bf16x8*)(L + AB1 + aoffs[2]);
        af3 = *(const bf16x8*)(L + AB1 + aoffs[3]);
        bf0 = *(const bf16x8*)(L + BB1 + boffs[0]);
        bf1 = *(const bf16x8*)(L + BB1 + boffs[1]);
        if (kt + 2 < NT) stageA(par, 0, kt + 2);
        __builtin_amdgcn_s_setprio(1);
        acc[0][0] = __builtin_amdgcn_mfma_f32_16x16x32_bf16(af0, bf0, acc[0][0], 0, 0, 0);
        acc[1][0] = __builtin_amdgcn_mfma_f32_16x16x32_bf16(af1, bf0, acc[1][0], 0, 0, 0);
        acc[2][0] = __builtin_amdgcn_mfma_f32_16x16x32_bf16(af2, bf0, acc[2][0], 0, 0, 0);
        acc[3][0] = __builtin_amdgcn_mfma_f32_16x16x32_bf16(af3, bf0, acc[3][0], 0, 0, 0);
        acc[0][1] = __builtin_amdgcn_mfma_f32_16x16x32_bf16(af0, bf1, acc[0][1], 0, 0, 0);
        acc[1][1] = __builtin_amdgcn_mfma_f32_16x16x32_bf16(af1, bf1, acc[1][1], 0, 0, 0);
        acc[2][1] = __builtin_amdgcn_mfma_f32_16x16x32_bf16(af2, bf1, acc[2][1], 0, 0, 0);
        acc[3][1] = __builtin_amdgcn_mfma_f32_16x16x32_bf16(af3, bf1, acc[3][1], 0, 0, 0);
        __builtin_amdgcn_s_setprio(0);
        asm volatile("s_waitcnt lgkmcnt(0)\n\ts_barrier" ::: "memory");

        // ---------- phase 3: ks=1, fj 2-3 ----------
        bf0 = *(const bf16x8*)(L + BB1 + boffs[2]);
        bf1 = *(const bf16x8*)(L + BB1 + boffs[3]);
        if (kt + 2 < NT) stageB(par, 0, kt + 2);
        __builtin_amdgcn_s_setprio(1);
        acc[0][2] = __builtin_amdgcn_mfma_f32_16x16x32_bf16(af0, bf0, acc[0][2], 0, 0, 0);
        acc[1][2] = __builtin_amdgcn_mfma_f32_16x16x32_bf16(af1, bf0, acc[1][2], 0, 0, 0);
        acc[2][2] = __builtin_amdgcn_mfma_f32_16x16x32_bf16(af2, bf0, acc[2][2], 0, 0, 0);
        acc[3][2] = __builtin_amdgcn_mfma_f32_16x16x32_bf16(af3, bf0, acc[3][2], 0, 0, 0);
        acc[0][3] = __builtin_amdgcn_mfma_f32_16x16x32_bf16(af0, bf1, acc[0][3], 0, 0, 0);
        acc[1][3] = __builtin_amdgcn_mfma_f32_16x16x32_bf16(af1, bf1, acc[1][3], 0, 0, 0);
        acc[2][3] = __builtin_amdgcn_mfma_f32_16x16x32_bf16(af2, bf1, acc[2][3], 0, 0, 0);
        acc[3][3] = __builtin_amdgcn_mfma_f32_16x16x32_bf16(af3, bf1, acc[3][3], 0, 0, 0);
        __builtin_amdgcn_s_setprio(0);
        asm volatile("s_waitcnt lgkmcnt(0)\n\ts_barrier" ::: "memory");
    }

    // C/D layout: col = lane&15, row = (lane>>4)*4 + reg  [m89-verified]
    const int rq = (lane >> 4) * 4;
#pragma unroll
    for (int fi = 0; fi < 4; ++fi) {
#pragma unroll
        for (int rg = 0; rg < 4; ++rg) {
            int row = m0 + wm * 64 + fi * 16 + rq + rg;
            float bm = (BIASMODE == 1) ? bias[row] : 0.f;
#pragma unroll
            for (int fj = 0; fj < 4; ++fj) {
                int col = n0 + wn * 64 + fj * 16 + fr;
                float vv = acc[fi][fj][rg] * alpha + bm;
                if (BIASMODE == 2) vv += bias[col];
                size_t off = (size_t)row * ldC + col;
                if (HASRES) vv += res[(size_t)bz * sR + off];
                if (OUTF32) ((float*)Cm)[(size_t)bz * sC + off] = vv;
                else ((unsigned short*)Cm)[(size_t)bz * sC + off] = f2bf(vv);
            }
        }
    }
}

// ---------------- in-place bf16 row softmax over 1024 ----------------
__global__ __launch_bounds__(256) void softmax_kernel(unsigned short* __restrict__ attn)
{
    size_t row = blockIdx.x;
    unsigned short* p = attn + row * HW_;
    ushort4 raw = reinterpret_cast<ushort4*>(p)[threadIdx.x];
    float v0 = bf2f(raw.x), v1 = bf2f(raw.y), v2 = bf2f(raw.z), v3 = bf2f(raw.w);

    float mx = fmaxf(fmaxf(v0, v1), fmaxf(v2, v3));
    for (int off = 32; off; off >>= 1) mx = fmaxf(mx, __shfl_down(mx, off, 64));
    __shared__ float redm[4], reds[4];
    int lane = threadIdx.x & 63, wid = threadIdx.x >> 6;
    if (lane == 0) redm[wid] = mx;
    __syncthreads();
    mx = fmaxf(fmaxf(redm[0], redm[1]), fmaxf(redm[2], redm[3]));

    v0 = __expf(v0 - mx); v1 = __expf(v1 - mx);
    v2 = __expf(v2 - mx); v3 = __expf(v3 - mx);
    float sum = v0 + v1 + v2 + v3;
    for (int off = 32; off; off >>= 1) sum += __shfl_down(sum, off, 64);
    if (lane == 0) reds[wid] = sum;
    __syncthreads();
    sum = reds[0] + reds[1] + reds[2] + reds[3];

    float inv = 1.f / sum;
    ushort4 o;
    o.x = f2bf(v0 * inv); o.y = f2bf(v1 * inv);
    o.z = f2bf(v2 * inv); o.w = f2bf(v3 * inv);
    reinterpret_cast<ushort4*>(p)[threadIdx.x] = o;
}

extern "C" void kernel_launch(void* const* d_in, const int* in_sizes, int n_in,
                              void* d_out, int out_size, void* d_ws, size_t ws_size,
                              hipStream_t stream)
{
    const float* x        = (const float*)d_in[0];
    // d_in[1] = temb : unused by the reference
    const float* gn_scale = (const float*)d_in[2];
    const float* gn_bias  = (const float*)d_in[3];
    const float* wq = (const float*)d_in[4];
    const float* bq = (const float*)d_in[5];
    const float* wk = (const float*)d_in[6];
    const float* bk = (const float*)d_in[7];
    const float* wv = (const float*)d_in[8];
    const float* bv = (const float*)d_in[9];
    const float* wo = (const float*)d_in[10];
    const float* bo = (const float*)d_in[11];
    float* out = (float*)d_out;

    // workspace layout (bf16 elements)
    short* ws = (short*)d_ws;
    const size_t E = (size_t)B_ * C_ * HW_;        // 8388608
    short* hn_t = ws;                              // [b][i][c]          E
    short* qk_t = hn_t + E;                        // [b*i][q||k]        2E
    short* v    = qk_t + 2 * E;                    // [b][c][j]          E
    short* ao_t = v + E;                           // [b][i][c]          E
    short* attn = ao_t + E;                        // [b][i][j]          2E
    short* wsq  = attn + 2 * E;                    // wq||wk||wv||wo bf16
    short* wsk  = wsq + (size_t)C_ * C_;
    short* wsv  = wsk + (size_t)C_ * C_;
    short* wso  = wsv + (size_t)C_ * C_;
    float* bqk  = (float*)(wso + (size_t)C_ * C_); // 1024 f32
    float2* stats = (float2*)(bqk + 1024);         // 512 float2

    const float inv_sqrt_c = 0.044194173824159216f;   // 512^-0.5

    f2bf4_kernel<<<dim3(1024), 256, 0, stream>>>(
        wq, wk, wv, wo,
        (unsigned short*)wsq, (unsigned short*)wsk,
        (unsigned short*)wsv, (unsigned short*)wso);
    bias_concat<<<dim3(2), 256, 0, stream>>>(bq, bk, bqk);

    gn_stats<<<dim3(B_ * G_), 256, 0, stream>>>(x, stats);
    gn_apply<<<dim3(HW_ / 64, C_ / 64, B_), 256, 0, stream>>>(
        x, stats, gn_scale, gn_bias, (unsigned short*)hn_t);

    // fused QK projection: qk_t[m][n] = sum_c hn_t[m][c] * (wq||wk)[n][c] + bqk[n]
    dim3 gqk(HW_ / 128, (B_ * HW_) / 256, 1);      // (8, 64, 1)
    gemm_8p<0, 2, 0><<<gqk, 512, 0, stream>>>(
        hn_t, 0, C_, wsq, 0, C_, qk_t, 0, HW_, bqk, nullptr, 0, C_, 1.0f);

    // v[c][j] = sum_k wv[c][k] * hn_t[j][k] + bv[c]
    dim3 gv(HW_ / 128, C_ / 256, B_);              // (8, 2, 16)
    gemm_8p<0, 1, 0><<<gv, 512, 0, stream>>>(
        wsv, 0, C_, hn_t, CHW, C_, v, CHW, HW_, bv, nullptr, 0, C_, 1.0f);

    // attn[i][j] = (sum_c q[i][c] * k[j][c]) * C^-0.5   (q,k inside qk_t)
    dim3 gs(HW_ / 128, HW_ / 256, B_);             // (8, 4, 16)
    gemm_8p<0, 0, 0><<<gs, 512, 0, stream>>>(
        qk_t, HW2, HW_, qk_t + C_, HW2, HW_, attn, HW2, HW_,
        nullptr, nullptr, 0, C_, inv_sqrt_c);

    softmax_kernel<<<dim3(B_ * HW_), 256, 0, stream>>>((unsigned short*)attn);

    // ao_t[i][c] = sum_j attn[i][j] * v[c][j]
    dim3 gp(C_ / 128, HW_ / 256, B_);              // (4, 4, 16)
    gemm_8p<0, 0, 0><<<gp, 512, 0, stream>>>(
        attn, HW2, HW_, v, CHW, HW_, ao_t, CHW, C_, nullptr, nullptr, 0, HW_, 1.0f);

    // out[c][i] = x + sum_k wo[c][k] * ao_t[i][k] + bo[c]
    dim3 go(HW_ / 128, C_ / 256, B_);              // (8, 2, 16)
    gemm_8p<1, 1, 1><<<go, 512, 0, stream>>>(
        wso, 0, C_, ao_t, CHW, C_, out, CHW, HW_, bo, x, CHW, C_, 1.0f);
}